// Round 4
// baseline (171.493 us; speedup 1.0000x reference)
//
#include <hip/hip_runtime.h>

// SLayer RBF pooling: out[b,n] = sum_p mask[b,p] * exp(-(s0*(c0-x0)^2 + s1*(c1-x1)^2))
// B=64, P=16384, N=64, D=2.
//
// Round 4: TIME-DILATION DIAGNOSTIC. R1-R3 totals (79.4/80.7/81.0 us) were
// insensitive to +-20 us of kernel-side change, and stage-1 never surfaced in
// the rocprof top-5 (hidden below the 41 us harness ws-poison fills). Here we
// repeat the R2 compute pass 8x (perturbed by runtime-zero `jitter` so the
// passes can't be CSE'd; result scaled by exact 0.125f) so stage-1 runs ~8x T
// and becomes visible in the profile. Branch:
//   dur ~80 unchanged  -> harness floor, kernel invisible -> ROOFLINE.
//   dur ~80 + 7T       -> kernel timed; stage-1 counters reveal the pipe.

#if __has_builtin(__builtin_amdgcn_exp2f)
#define EXP2(x) __builtin_amdgcn_exp2f(x)
#else
#define EXP2(x) exp2f(x)
#endif

constexpr int BATCH  = 64;
constexpr int P      = 16384;
constexpr int N      = 64;
constexpr int CHUNKS = 16;            // point-chunks per batch
constexpr int CHUNK  = P / CHUNKS;    // 1024 points per block
constexpr int BLOCK  = 256;           // 4 waves
constexpr int WPTS   = CHUNK / 4;     // 256 points per wave
constexpr int REPEAT = 8;             // diagnostic work multiplier

__global__ __launch_bounds__(BLOCK) void slayer_stage1(
    const float* __restrict__ batch,
    const float* __restrict__ mask,
    const float* __restrict__ centers,
    const float* __restrict__ sharp,
    float* __restrict__ partial,      // [B][CHUNKS][N]
    float jitter)                     // runtime 0.0f — defeats cross-pass CSE
{
    __shared__ float red[4][N];

    const int b     = blockIdx.x >> 4;
    const int chunk = blockIdx.x & (CHUNKS - 1);
    const int tid   = threadIdx.x;
    const int lane  = tid & 63;
    const int wave  = __builtin_amdgcn_readfirstlane(tid >> 6);  // SGPR wave id

    // per-lane center coefficients (lane = n)
    const float c0 = centers[2 * lane], c1 = centers[2 * lane + 1];
    const float s0 = sharp[2 * lane],  s1 = sharp[2 * lane + 1];
    const float L  = 1.4426950408889634f;     // log2(e)
    const float C0 = -L * s0, C1 = -L * s1;
    const float B0 = -2.0f * C0 * c0, B1 = -2.0f * C1 * c1;
    const float A  = C0 * c0 * c0 + C1 * c1 * c1;

    // wave-uniform point range: 256 contiguous points
    const size_t pbase = (size_t)b * P + (size_t)chunk * CHUNK + (size_t)wave * WPTS;
    const float4* __restrict__ xy = (const float4*)(batch + pbase * 2); // 2 float4 / 4 pts
    const float4* __restrict__ mk = (const float4*)(mask + pbase);     // 1 float4 / 4 pts

    float acc0 = 0.f, acc1 = 0.f, acc2 = 0.f, acc3 = 0.f;
    #pragma unroll 1
    for (int r = 0; r < REPEAT; ++r) {
        const float Ar = fmaf((float)r, jitter, A);  // == A at runtime
        #pragma unroll 4
        for (int g = 0; g < WPTS / 4; ++g) {
            float4 v0 = xy[2 * g];
            float4 v1 = xy[2 * g + 1];
            float4 m  = mk[g];
            float ta = fmaf(v0.x, fmaf(C0, v0.x, B0), fmaf(v0.y, fmaf(C1, v0.y, B1), Ar));
            float tb = fmaf(v0.z, fmaf(C0, v0.z, B0), fmaf(v0.w, fmaf(C1, v0.w, B1), Ar));
            float tc = fmaf(v1.x, fmaf(C0, v1.x, B0), fmaf(v1.y, fmaf(C1, v1.y, B1), Ar));
            float td = fmaf(v1.z, fmaf(C0, v1.z, B0), fmaf(v1.w, fmaf(C1, v1.w, B1), Ar));
            acc0 = fmaf(m.x, EXP2(ta), acc0);
            acc1 = fmaf(m.y, EXP2(tb), acc1);
            acc2 = fmaf(m.z, EXP2(tc), acc2);
            acc3 = fmaf(m.w, EXP2(td), acc3);
        }
    }
    // 8 identical passes summed -> scale by exact 1/8 (power of 2, lossless)
    float acc = ((acc0 + acc1) + (acc2 + acc3)) * (1.0f / REPEAT);

    // reduce 4 waves via 1 KB LDS, write 64 coalesced partials
    red[wave][lane] = acc;
    __syncthreads();
    if (tid < N) {
        float s = red[0][tid] + red[1][tid] + red[2][tid] + red[3][tid];
        partial[((size_t)b * CHUNKS + chunk) * N + tid] = s;
    }
}

__global__ __launch_bounds__(256) void slayer_stage2(
    const float* __restrict__ partial,   // [B][CHUNKS][N]
    float* __restrict__ out)             // [B][N]
{
    const int idx = blockIdx.x * 256 + threadIdx.x;   // 4096 outputs
    const int b = idx >> 6, n = idx & 63;
    float s = 0.f;
    #pragma unroll
    for (int c = 0; c < CHUNKS; ++c)
        s += partial[((size_t)b * CHUNKS + c) * N + n];  // coalesced in n
    out[idx] = s;
}

extern "C" void kernel_launch(void* const* d_in, const int* in_sizes, int n_in,
                              void* d_out, int out_size, void* d_ws, size_t ws_size,
                              hipStream_t stream) {
    const float* batch   = (const float*)d_in[0];
    const float* mask    = (const float*)d_in[1];
    const float* centers = (const float*)d_in[2];
    const float* sharp   = (const float*)d_in[3];
    float* out     = (float*)d_out;
    float* partial = (float*)d_ws;   // 64*16*64*4 = 256 KB << ws_size

    slayer_stage1<<<BATCH * CHUNKS, BLOCK, 0, stream>>>(batch, mask, centers, sharp,
                                                        partial, 0.0f);
    slayer_stage2<<<(BATCH * N) / 256, 256, 0, stream>>>(partial, out);
}

// Round 5
// 79.902 us; speedup vs baseline: 2.1463x; 2.1463x over previous
//
#include <hip/hip_runtime.h>

// SLayer RBF pooling: out[b,n] = sum_p mask[b,p] * exp(-(s0*(c0-x0)^2 + s1*(c1-x1)^2))
// B=64, P=16384, N=64, D=2.
//
// R4 findings: kernel is VALU-issue-bound at 26 cyc/point-wave
// (4 t-FMAs=8cyc + acc-FMA=2cyc + v_exp_f32~16cyc); VALUBusy 73%, loads fully
// scalarized (SGPR=80), FETCH=12.3MB (no over-fetch). Total = ~60us harness
// floor + ~15us kernel + ~2us stage2.
//
// Round 5 (safe changes only, math untouched):
//  1. CHUNKS 16->32: 2048 blocks x 4 waves = 8192 waves = exactly 8 waves/SIMD
//     (VGPR=24 allows it) -> fill the 14-27% issue gap from load waits/churn.
//  2. Fuse stage-2: 16KB memset + one atomicAdd per (b,n) per block replaces
//     the separate reduction dispatch (R1-style epilogue).

#if __has_builtin(__builtin_amdgcn_exp2f)
#define EXP2(x) __builtin_amdgcn_exp2f(x)
#else
#define EXP2(x) exp2f(x)
#endif

constexpr int BATCH  = 64;
constexpr int P      = 16384;
constexpr int N      = 64;
constexpr int CHUNKS = 32;            // point-chunks per batch
constexpr int CHUNK  = P / CHUNKS;    // 512 points per block
constexpr int BLOCK  = 256;           // 4 waves
constexpr int WPTS   = CHUNK / 4;     // 128 points per wave

__global__ __launch_bounds__(BLOCK) void slayer_rbf(
    const float* __restrict__ batch,
    const float* __restrict__ mask,
    const float* __restrict__ centers,
    const float* __restrict__ sharp,
    float* __restrict__ out)          // [B][N], pre-zeroed
{
    __shared__ float red[4][N];

    const int b     = blockIdx.x >> 5;            // / CHUNKS
    const int chunk = blockIdx.x & (CHUNKS - 1);
    const int tid   = threadIdx.x;
    const int lane  = tid & 63;
    const int wave  = __builtin_amdgcn_readfirstlane(tid >> 6);  // SGPR wave id

    // per-lane center coefficients (lane = n)
    const float c0 = centers[2 * lane], c1 = centers[2 * lane + 1];
    const float s0 = sharp[2 * lane],  s1 = sharp[2 * lane + 1];
    const float L  = 1.4426950408889634f;     // log2(e)
    const float C0 = -L * s0, C1 = -L * s1;
    const float B0 = -2.0f * C0 * c0, B1 = -2.0f * C1 * c1;
    const float A  = C0 * c0 * c0 + C1 * c1 * c1;

    // wave-uniform point range: 128 contiguous points (scalarized loads)
    const size_t pbase = (size_t)b * P + (size_t)chunk * CHUNK + (size_t)wave * WPTS;
    const float4* __restrict__ xy = (const float4*)(batch + pbase * 2); // 2 float4 / 4 pts
    const float4* __restrict__ mk = (const float4*)(mask + pbase);     // 1 float4 / 4 pts

    float acc0 = 0.f, acc1 = 0.f, acc2 = 0.f, acc3 = 0.f;
    #pragma unroll 8
    for (int g = 0; g < WPTS / 4; ++g) {
        float4 v0 = xy[2 * g];
        float4 v1 = xy[2 * g + 1];
        float4 m  = mk[g];
        float ta = fmaf(v0.x, fmaf(C0, v0.x, B0), fmaf(v0.y, fmaf(C1, v0.y, B1), A));
        float tb = fmaf(v0.z, fmaf(C0, v0.z, B0), fmaf(v0.w, fmaf(C1, v0.w, B1), A));
        float tc = fmaf(v1.x, fmaf(C0, v1.x, B0), fmaf(v1.y, fmaf(C1, v1.y, B1), A));
        float td = fmaf(v1.z, fmaf(C0, v1.z, B0), fmaf(v1.w, fmaf(C1, v1.w, B1), A));
        acc0 = fmaf(m.x, EXP2(ta), acc0);
        acc1 = fmaf(m.y, EXP2(tb), acc1);
        acc2 = fmaf(m.z, EXP2(tc), acc2);
        acc3 = fmaf(m.w, EXP2(td), acc3);
    }
    float acc = (acc0 + acc1) + (acc2 + acc3);

    // fused epilogue: reduce 4 waves via 1 KB LDS, one atomicAdd per (b,n)
    red[wave][lane] = acc;
    __syncthreads();
    if (tid < N) {
        float s = red[0][tid] + red[1][tid] + red[2][tid] + red[3][tid];
        atomicAdd(&out[b * N + tid], s);
    }
}

extern "C" void kernel_launch(void* const* d_in, const int* in_sizes, int n_in,
                              void* d_out, int out_size, void* d_ws, size_t ws_size,
                              hipStream_t stream) {
    const float* batch   = (const float*)d_in[0];
    const float* mask    = (const float*)d_in[1];
    const float* centers = (const float*)d_in[2];
    const float* sharp   = (const float*)d_in[3];
    float* out = (float*)d_out;

    // d_out is poisoned 0xAA before every call; zero 16 KB for the atomic adds.
    hipMemsetAsync(out, 0, (size_t)out_size * sizeof(float), stream);
    slayer_rbf<<<BATCH * CHUNKS, BLOCK, 0, stream>>>(batch, mask, centers, sharp, out);
}